// Round 1
// baseline (176.380 us; speedup 1.0000x reference)
//
#include <hip/hip_runtime.h>

// Covariance: B=8, T=512, F=513, M=8, AVERAGE=True
// out(b,t,f,c,p) = mean_t[ products ]  (broadcast over t)
constexpr int kB = 8;
constexpr int kT = 512;
constexpr int kF = 513;
constexpr int kM = 8;
constexpr int kNP = 36;           // M*(M+1)/2 upper-tri pairs
constexpr int kC = 2 * kNP;       // 72 floats per (b,t,f)

// One block per (b,f). 256 threads, each handles t = tid and tid+256.
__global__ __launch_bounds__(256) void cov_reduce(const float* __restrict__ in,
                                                  float* __restrict__ out) {
  const int bf = blockIdx.x;          // 0 .. B*F-1
  const int b = bf / kF;
  const int f = bf - b * kF;
  const int tid = threadIdx.x;

  float accR[kNP], accI[kNP];
#pragma unroll
  for (int p = 0; p < kNP; ++p) { accR[p] = 0.0f; accI[p] = 0.0f; }

#pragma unroll
  for (int s = 0; s < 2; ++s) {
    const int t = tid + s * 256;
    const float* ptr = in + (((size_t)b * kT + t) * kF + f) * (2 * kM);
    const float4 r0 = *(const float4*)(ptr + 0);
    const float4 r1 = *(const float4*)(ptr + 4);
    const float4 i0 = *(const float4*)(ptr + 8);
    const float4 i1 = *(const float4*)(ptr + 12);
    const float re[kM] = {r0.x, r0.y, r0.z, r0.w, r1.x, r1.y, r1.z, r1.w};
    const float im[kM] = {i0.x, i0.y, i0.z, i0.w, i1.x, i1.y, i1.z, i1.w};
    int p = 0;
#pragma unroll
    for (int i = 0; i < kM; ++i) {
#pragma unroll
      for (int j = i; j < kM; ++j) {
        accR[p] += re[i] * re[j] + im[i] * im[j];
        accI[p] += re[i] * im[j] - im[i] * re[j];
        ++p;
      }
    }
  }

  // 64-lane butterfly reduction over the wave
#pragma unroll
  for (int off = 32; off >= 1; off >>= 1) {
#pragma unroll
    for (int p = 0; p < kNP; ++p) {
      accR[p] += __shfl_xor(accR[p], off, 64);
      accI[p] += __shfl_xor(accI[p], off, 64);
    }
  }

  // combine the 4 waves through LDS
  __shared__ float lds[4][kC];
  const int wave = tid >> 6;
  const int lane = tid & 63;
  if (lane == 0) {
#pragma unroll
    for (int p = 0; p < kNP; ++p) {
      lds[wave][p] = accR[p];
      lds[wave][kNP + p] = accI[p];
    }
  }
  __syncthreads();
  if (tid < kC) {
    const float ssum = lds[0][tid] + lds[1][tid] + lds[2][tid] + lds[3][tid];
    // write the mean into the t=0 slice of the output (part of the answer)
    out[(((size_t)b * kT + 0) * kF + f) * kC + tid] = ssum * (1.0f / kT);
  }
}

// Broadcast the t=0 slice to all t. One thread per output float4.
__global__ __launch_bounds__(256) void cov_bcast(float4* __restrict__ out) {
  const unsigned total4 = (unsigned)kB * kT * kF * (kC / 4);  // 37,822,464
  const unsigned idx = blockIdx.x * 256u + threadIdx.x;
  if (idx >= total4) return;
  const unsigned g = idx / (kC / 4);          // (b*T + t)*F + f
  const unsigned r = idx - g * (kC / 4);      // float4 index within the 72
  const unsigned b = g / (unsigned)(kT * kF);
  const unsigned f = g % (unsigned)kF;        // ((b*T+t)*F) is a multiple of F
  const unsigned src = (b * (unsigned)(kT * kF) + f) * (kC / 4) + r;
  out[idx] = out[src];   // t=0: self-copy of identical value (benign)
}

extern "C" void kernel_launch(void* const* d_in, const int* in_sizes, int n_in,
                              void* d_out, int out_size, void* d_ws, size_t ws_size,
                              hipStream_t stream) {
  const float* in = (const float*)d_in[0];
  float* out = (float*)d_out;

  // Stage 1: per-(b,f) reduction over T, mean written into t=0 slice of out
  cov_reduce<<<dim3(kB * kF), dim3(256), 0, stream>>>(in, out);

  // Stage 2: broadcast t=0 slice across all t
  const unsigned total4 = (unsigned)kB * kT * kF * (kC / 4);
  cov_bcast<<<dim3((total4 + 255u) / 256u), dim3(256), 0, stream>>>((float4*)out);
}

// Round 2
// 147.148 us; speedup vs baseline: 1.1987x; 1.1987x over previous
//
#include <hip/hip_runtime.h>

// Covariance: B=8, T=512, F=513, M=8, AVERAGE=True
// out(b,t,f,c,p) = mean over t of upper-tri complex cross-products, broadcast over t.
constexpr int kB  = 8;
constexpr int kT  = 512;
constexpr int kF  = 513;
constexpr int kM  = 8;
constexpr int kNP = 36;        // M*(M+1)/2 pairs
constexpr int kC  = 2 * kNP;   // 72 floats per (b,t,f)
constexpr int kFT = 64;        // f-tile width (= wave)
constexpr int kNFT = 9;        // ceil(F/64)
constexpr int kTC = 64;        // t-chunk
constexpr int kNTC = 8;        // T/kTC
constexpr int kLDP = kC + 1;   // LDS row pad (73: conflict-free, 73%32=9, gcd(9,32)=1)

// Stage 1: one block per (b, f-tile, t-chunk). Lane = f (coalesced 4KB/wave reads).
// Each of 4 waves covers t = t0+wave, step 4. Cross-wave combine via LDS.
// Partial sums written to output t-slices 1..8 (scratch, overwritten by bcast).
__global__ __launch_bounds__(256) void cov_partial(const float* __restrict__ in,
                                                   float* __restrict__ out) {
  const int bx = blockIdx.x;
  const int b  = bx / (kNFT * kNTC);
  const int r  = bx - b * (kNFT * kNTC);
  const int ft = r / kNTC;
  const int tc = r - ft * kNTC;
  const int tid  = threadIdx.x;
  const int wave = tid >> 6;
  const int lane = tid & 63;
  const int f = ft * kFT + lane;

  float accR[kNP], accI[kNP];
#pragma unroll
  for (int p = 0; p < kNP; ++p) { accR[p] = 0.0f; accI[p] = 0.0f; }

  if (f < kF) {
    const int t0 = tc * kTC + wave;
    const float* base = in + ((size_t)(b * kT + t0) * kF + f) * (2 * kM);
    const size_t tstep = (size_t)4 * kF * (2 * kM);   // advance 4 t's
#pragma unroll 2
    for (int it = 0; it < kTC / 4; ++it) {
      const float* ptr = base + it * tstep;
      const float4 r0 = *(const float4*)(ptr + 0);
      const float4 r1 = *(const float4*)(ptr + 4);
      const float4 i0 = *(const float4*)(ptr + 8);
      const float4 i1 = *(const float4*)(ptr + 12);
      const float re[kM] = {r0.x, r0.y, r0.z, r0.w, r1.x, r1.y, r1.z, r1.w};
      const float im[kM] = {i0.x, i0.y, i0.z, i0.w, i1.x, i1.y, i1.z, i1.w};
      int p = 0;
#pragma unroll
      for (int i = 0; i < kM; ++i) {
#pragma unroll
        for (int j = i; j < kM; ++j) {
          accR[p] += re[i] * re[j] + im[i] * im[j];
          accI[p] += re[i] * im[j] - im[i] * re[j];
          ++p;
        }
      }
    }
  }

  // combine 4 waves (disjoint t) -> 2 LDS buffers -> sum on write-out
  __shared__ float buf[2][kFT * kLDP];
  float* my = buf[wave & 1] + lane * kLDP;
  if (wave < 2) {
#pragma unroll
    for (int p = 0; p < kNP; ++p) { my[p] = accR[p]; my[kNP + p] = accI[p]; }
  }
  __syncthreads();
  if (wave >= 2) {
#pragma unroll
    for (int p = 0; p < kNP; ++p) { my[p] += accR[p]; my[kNP + p] += accI[p]; }
  }
  __syncthreads();

  const int nf = min(kFT, kF - ft * kFT);
  float* dst = out + ((size_t)(b * kT + (1 + tc)) * kF + ft * kFT) * kC;
  const int n = nf * kC;
  for (int e = tid; e < n; e += 256) {
    const int l = (unsigned)e / (unsigned)kC;     // magic-mul
    const int p = e - l * kC;
    dst[e] = buf[0][l * kLDP + p] + buf[1][l * kLDP + p];
  }
}

// Stage 2: sum the 8 partial slices (t=1..8), scale by 1/T, write t=0 slice.
__global__ __launch_bounds__(256) void cov_combine(float* __restrict__ out) {
  const int total = kB * kF * kC;                  // 295,488
  const int idx = blockIdx.x * 256 + threadIdx.x;
  if (idx >= total) return;
  const int b = (unsigned)idx / (unsigned)(kF * kC);
  const int rem = idx - b * (kF * kC);
  const size_t bbase = (size_t)b * kT * kF * kC;
  float s = 0.0f;
#pragma unroll
  for (int k = 0; k < kNTC; ++k)
    s += out[bbase + (size_t)(1 + k) * (kF * kC) + rem];
  out[bbase + rem] = s * (1.0f / kT);
}

// Stage 3: broadcast t=0 slice to all t. One thread per output float4.
__global__ __launch_bounds__(256) void cov_bcast(float4* __restrict__ out) {
  const unsigned total4 = (unsigned)kB * kT * kF * (kC / 4);  // 37,822,464
  const unsigned idx = blockIdx.x * 256u + threadIdx.x;
  if (idx >= total4) return;
  const unsigned g = idx / (kC / 4);          // (b*T + t)*F + f
  const unsigned r = idx - g * (kC / 4);
  const unsigned b = g / (unsigned)(kT * kF);
  const unsigned f = g % (unsigned)kF;
  const unsigned src = (b * (unsigned)(kT * kF) + f) * (kC / 4) + r;
  out[idx] = out[src];   // t=0 is a value-identical self-copy
}

extern "C" void kernel_launch(void* const* d_in, const int* in_sizes, int n_in,
                              void* d_out, int out_size, void* d_ws, size_t ws_size,
                              hipStream_t stream) {
  const float* in = (const float*)d_in[0];
  float* out = (float*)d_out;

  cov_partial<<<dim3(kB * kNFT * kNTC), dim3(256), 0, stream>>>(in, out);

  const int total = kB * kF * kC;
  cov_combine<<<dim3((total + 255) / 256), dim3(256), 0, stream>>>(out);

  const unsigned total4 = (unsigned)kB * kT * kF * (kC / 4);
  cov_bcast<<<dim3((total4 + 255u) / 256u), dim3(256), 0, stream>>>((float4*)out);
}